// Round 8
// baseline (396.000 us; speedup 1.0000x reference)
//
#include <hip/hip_runtime.h>
#include <hip/hip_fp16.h>
#include <math.h>

// Problem constants
#define V    20000
#define SCV  4000
#define LL   15
#define OUTN (16384 * 128)   // B*S*D

#define LEAF_BIT 0x40000000
#define REF_MASK 0x3FFFFFFF
#define DUMMY_SLOT 89999     // total internal nodes < 90000

// ---- workspace layout (bytes) ----
// counts int[32] @0 ; rootSlot int[V] @128 ; lists int4[240000] @80384
// leafC f32[4000*128] @3920384 ; leafHh fp16 @5968384 ; embB fp16[4000*640] @6992384
// WT fp16[640*256] @12112384 ; cInt f32[90000*128] @12440064 ; hH fp16 @58520064
// total ~81.6 MB
#define OFF_COUNTS 0
#define OFF_ROOT   128
#define OFF_LISTS  80384
#define OFF_LEAFC  3920384
#define OFF_LEAFHH 5968384
#define OFF_EMBB   6992384
#define OFF_WT     12112384
#define OFF_CINT   12440064
#define OFF_HH     58520064

// per-height lists: h1@0 (cap 80000), h2@80000 (40000), h3@120000 (40000),
// h4@160000, h5@180000, h6@200000, h7@220000 (20000 each)
__device__ __constant__ int d_listOff[8] = {0, 0, 80000, 120000, 160000, 180000, 200000, 220000};

#define ROUND_BLOCKS 1920

typedef _Float16 f16x8 __attribute__((ext_vector_type(8)));
typedef float    f32x4 __attribute__((ext_vector_type(4)));

__device__ __forceinline__ float sigm(float x) { return 1.0f / (1.0f + expf(-x)); }

// ---------------- prep: leaf h/c + embB (= emb + biases, fp16) + WT transpose ----------------
__global__ void prep_kernel(const float* __restrict__ emb,
                            const float* __restrict__ Wl, const float* __restrict__ Wlb,
                            const float* __restrict__ Wr, const float* __restrict__ Wrb,
                            float* __restrict__ leafC, __half* __restrict__ leafHh,
                            __half* __restrict__ embB, __half* __restrict__ WT) {
    int b = blockIdx.x, t = threadIdx.x;
    if (b < 2000) {                         // leaf states: 2 rows per block
        int row = b * 2 + (t >> 7);
        int i = t & 127;
        const float* e = emb + row * 640;
        float c = sigm(e[i]) * tanhf(e[512 + i]);
        float h = sigm(e[384 + i]) * tanhf(c);
        leafC[row * 128 + i] = c;
        leafHh[row * 128 + i] = __float2half(h);
    } else if (b < 4560) {                  // embB: 2,560,000 halves
        for (int i = (b - 2000) * 256 + t; i < 2560000; i += 2560 * 256) {
            int col = i % 640;
            embB[i] = __float2half(emb[i] + Wlb[col] + Wrb[col]);
        }
    } else {                                // WT[n][k] = fp16([Wl;Wr]^T), 640*256
        for (int i = (b - 4560) * 256 + t; i < 163840; i += 64 * 256) {
            int n = i >> 8, k = i & 255;
            float w = (k < 128) ? Wl[k * 640 + n] : Wr[(k - 128) * 640 + n];
            WT[i] = __float2half(w);
        }
    }
}

// ---------------- metadata: heights, compact slots, per-height lists ----------------
#define MT 128
__global__ void meta_kernel(const int* __restrict__ node_ids,
                            const int* __restrict__ left,
                            const int* __restrict__ right,
                            const int* __restrict__ last,
                            int* __restrict__ counts,
                            int* __restrict__ rootSlot,
                            int4* __restrict__ lists) {
    __shared__ int  sHei[MT][17];
    __shared__ int  sRef[MT][17];
    __shared__ int4 ebuf[MT][7];
    __shared__ int  ebin[MT][7];
    __shared__ int  locCnt[8];
    __shared__ int  basePos[8];
    __shared__ int  scanBuf[MT];
    __shared__ int  blockBase;

    int tid = threadIdx.x;
    if (tid < 8) locCnt[tid] = 0;
    __syncthreads();

    int v = blockIdx.x * MT + tid;
    int nInt = 0;
    if (v < V) {
        int l15[LL], r15[LL], id15[LL];
#pragma unroll
        for (int j = 0; j < LL; ++j) {
            l15[j]  = left[v * LL + j];
            r15[j]  = right[v * LL + j];
            id15[j] = node_ids[v * LL + j];
        }
        int lastv = last[v];
#pragma unroll
        for (int j = 0; j < LL; ++j) {
            if (j <= lastv) {
                int l = l15[j];
                if (l < 0) {
                    sHei[tid][j] = 0;
                    sRef[tid][j] = LEAF_BIT | id15[j];
                } else {
                    int r = r15[j];
                    int hl = sHei[tid][l], hr = sHei[tid][r];
                    int hh = 1 + (hl > hr ? hl : hr);
                    sHei[tid][j] = hh;
                    int pos = atomicAdd(&locCnt[hh], 1);
                    ebuf[tid][nInt] = make_int4(nInt, id15[j], sRef[tid][l], sRef[tid][r]);
                    ebin[tid][nInt] = (hh << 16) | pos;
                    sRef[tid][j] = nInt;    // local slot index (no LEAF_BIT)
                    ++nInt;
                }
            }
        }
    }
    // block-level inclusive scan of nInt -> compact slot bases
    scanBuf[tid] = nInt;
    __syncthreads();
    for (int d = 1; d < MT; d <<= 1) {
        int val = (tid >= d) ? scanBuf[tid - d] : 0;
        __syncthreads();
        scanBuf[tid] += val;
        __syncthreads();
    }
    if (tid == 0) blockBase = atomicAdd(&counts[31], scanBuf[MT - 1]);
    if (tid < 8) {
        int c = locCnt[tid];
        basePos[tid] = c ? atomicAdd(&counts[tid], c) : 0;
    }
    __syncthreads();
    int treeBase = blockBase + scanBuf[tid] - nInt;
    if (v < V) rootSlot[v] = treeBase + nInt - 1;
    for (int e = 0; e < nInt; ++e) {
        int4 E  = ebuf[tid][e];
        int md  = ebin[tid][e];
        int hh  = md >> 16, pos = md & 0xFFFF;
        E.x += treeBase;
        E.z = (E.z & LEAF_BIT) ? E.z : (E.z + treeBase);   // keep leaf tag
        E.w = (E.w & LEAF_BIT) ? E.w : (E.w + treeBase);
        lists[d_listOff[hh] + basePos[hh] + pos] = E;
    }
}

// ---------------- MFMA round: all internal nodes of one height, K=256 ----------------
// chunk = 16 nodes. acc starts at ZERO -> K-loop never waits on gathers.
// embB rows staged coalesced to LDS (stride 644: conflict-free epilogue reads);
// cl/cr prefetched to registers before the K-loop.
__launch_bounds__(256)
__global__ void round_mfma(const int4* __restrict__ list, const int* __restrict__ cntPtr,
                           const __half* __restrict__ embB, const __half* __restrict__ WT,
                           const __half* __restrict__ leafHh, const float* __restrict__ leafC,
                           float* __restrict__ cInt, __half* __restrict__ hH) {
    __shared__ __half Ah[16][264];   // A rows [hl | hr] fp16, +8 pad
    __shared__ __half Eb[16][644];   // embB rows; stride%16==4 -> 2-way-only epilogue
    __shared__ int4 meta[16];
    int cnt = *cntPtr;
    int nChunks = (cnt + 15) >> 4;
    int t = threadIdx.x;
    int lane = t & 63, wave = t >> 6;        // 4 waves
    int ln15 = lane & 15, quad = lane >> 4;
    for (int chunk = blockIdx.x; chunk < nChunks; chunk += gridDim.x) {
        int base = chunk * 16;
        int rows = cnt - base; if (rows > 16) rows = 16;
        if (t < 16) {
            int4 E;
            if (t < rows) E = list[base + t];
            else { E.x = DUMMY_SLOT; E.y = 0; E.z = LEAF_BIT; E.w = LEAF_BIT; }
            meta[t] = E;
        }
        __syncthreads();
        // stage A rows: [hl fp16 (k 0..127) | hr fp16 (k 128..255)]
        for (int idx = t; idx < 512; idx += 256) {
            int m = idx >> 5, q = idx & 31;
            int ref = (q < 16) ? meta[m].z : meta[m].w;
            const __half* hs = (ref & LEAF_BIT) ? leafHh : hH;
            uint4 v = *(const uint4*)(hs + (ref & REF_MASK) * 128 + (q & 15) * 8);
            *(uint4*)(&Ah[m][q * 8]) = v;
        }
        // stage embB rows (coalesced 8B)
        for (int idx = t; idx < 2560; idx += 256) {
            int m = idx / 160, q = idx - m * 160;
            uint2 v = *(const uint2*)(embB + meta[m].y * 640 + q * 4);
            *(uint2*)(&Eb[m][q * 4]) = v;
        }
        // prefetch children c (consumed only in epilogue)
        float clv[2][4], crv[2][4];
#pragma unroll
        for (int g = 0; g < 2; ++g) {
            int d = (wave + 4 * g) * 16 + ln15;
#pragma unroll
            for (int r = 0; r < 4; ++r) {
                int4 E = meta[quad * 4 + r];
                clv[g][r] = ((E.z & LEAF_BIT) ? leafC : cInt)[(E.z & REF_MASK) * 128 + d];
                crv[g][r] = ((E.w & LEAF_BIT) ? leafC : cInt)[(E.w & REF_MASK) * 128 + d];
            }
        }
        f32x4 acc[10];
#pragma unroll
        for (int p = 0; p < 10; ++p) acc[p] = (f32x4){0.f, 0.f, 0.f, 0.f};
        __syncthreads();
        // K loop: 8 steps of 32; no global dependency
#pragma unroll 1
        for (int kb = 0; kb < 8; ++kb) {
            f16x8 af = *(const f16x8*)((const void*)&Ah[ln15][kb * 32 + quad * 8]);
#pragma unroll
            for (int p = 0; p < 10; ++p) {
                const __half* bp = WT + ((wave + 4 * p) * 16 + ln15) * 256 + kb * 32 + quad * 8;
                f16x8 bf = *(const f16x8*)((const void*)bp);
                acc[p] = __builtin_amdgcn_mfma_f32_16x16x32_f16(af, bf, acc[p], 0, 0, 0);
            }
        }
        // in-register LSTM epilogue: gate g5 of dim-group g at acc[2*g5+g]
#pragma unroll
        for (int g = 0; g < 2; ++g) {
            int d = (wave + 4 * g) * 16 + ln15;   // dim in [0,128)
#pragma unroll
            for (int r = 0; r < 4; ++r) {
                int m = quad * 4 + r;
                int dst = meta[m].x;
                float ig  = acc[g][r]     + __half2float(Eb[m][d]);
                float lfg = acc[2 + g][r] + __half2float(Eb[m][128 + d]);
                float rfg = acc[4 + g][r] + __half2float(Eb[m][256 + d]);
                float og  = acc[6 + g][r] + __half2float(Eb[m][384 + d]);
                float ug  = acc[8 + g][r] + __half2float(Eb[m][512 + d]);
                float c = sigm(ig) * tanhf(ug) + sigm(lfg) * clv[g][r] + sigm(rfg) * crv[g][r];
                float h = sigm(og) * tanhf(c);
                cInt[dst * 128 + d] = c;
                hH[dst * 128 + d] = __float2half(h);
            }
        }
        __syncthreads();   // protect meta/Ah/Eb before next chunk
    }
}

// ---------------- final gather: out[b,s,:] = fp32(hH[root(input[b,s])]) ----------------
__global__ void gather_kernel(const int* __restrict__ input,
                              const int* __restrict__ rootSlot,
                              const __half* __restrict__ hH,
                              float4* __restrict__ out) {
    int idx = blockIdx.x * 256 + threadIdx.x;   // < OUTN/4
    int token = input[idx >> 5];
    int d = idx & 31;
    uint2 v = ((const uint2*)hH)[rootSlot[token] * 32 + d];
    float2 fa = __half22float2(*(__half2*)&v.x);
    float2 fb = __half22float2(*(__half2*)&v.y);
    out[idx] = make_float4(fa.x, fa.y, fb.x, fb.y);
}

extern "C" void kernel_launch(void* const* d_in, const int* in_sizes, int n_in,
                              void* d_out, int out_size, void* d_ws, size_t ws_size,
                              hipStream_t stream) {
    const int*   input    = (const int*)d_in[0];
    const int*   node_ids = (const int*)d_in[1];
    const int*   left     = (const int*)d_in[2];
    const int*   right    = (const int*)d_in[3];
    const int*   last     = (const int*)d_in[4];
    const float* emb      = (const float*)d_in[5];
    const float* Wl       = (const float*)d_in[6];
    const float* Wlb      = (const float*)d_in[7];
    const float* Wr       = (const float*)d_in[8];
    const float* Wrb      = (const float*)d_in[9];
    float* out = (float*)d_out;

    char* ws = (char*)d_ws;
    int*    counts   = (int*)(ws + OFF_COUNTS);
    int*    rootSlot = (int*)(ws + OFF_ROOT);
    int4*   lists    = (int4*)(ws + OFF_LISTS);
    float*  leafC    = (float*)(ws + OFF_LEAFC);
    __half* leafHh   = (__half*)(ws + OFF_LEAFHH);
    __half* embB     = (__half*)(ws + OFF_EMBB);
    __half* WT       = (__half*)(ws + OFF_WT);
    float*  cInt     = (float*)(ws + OFF_CINT);
    __half* hH       = (__half*)(ws + OFF_HH);

    (void)hipMemsetAsync(counts, 0, 128, stream);

    prep_kernel<<<4624, 256, 0, stream>>>(emb, Wl, Wlb, Wr, Wrb, leafC, leafHh, embB, WT);
    meta_kernel<<<(V + MT - 1) / MT, MT, 0, stream>>>(node_ids, left, right, last,
                                                      counts, rootSlot, lists);

    static const int h_listOff[8] = {0, 0, 80000, 120000, 160000, 180000, 200000, 220000};
    for (int h = 1; h <= 7; ++h) {
        round_mfma<<<ROUND_BLOCKS, 256, 0, stream>>>(
            lists + h_listOff[h], counts + h,
            embB, WT, leafHh, leafC, cInt, hH);
    }

    gather_kernel<<<OUTN / 4 / 256, 256, 0, stream>>>(input, rootSlot, hH, (float4*)out);
}